// Round 3
// baseline (43.278 us; speedup 1.0000x reference)
//
#include <hip/hip_runtime.h>
#include <hip/hip_cooperative_groups.h>

namespace cg = cooperative_groups;

typedef float f4 __attribute__((ext_vector_type(4)));

// Problem constants: B=8, N=8192, K=16, C_in=C_out=64
#define BB 8
#define NN 8192
#define KK 16
#define CC 64
#define TPB 64                   // tokens per chunk
#define THREADS 256
#define NCHUNK 1024              // 8 batches * 128 chunks
#define NTOK (BB * NN)
#define BN_EPS 1e-5f

// Compute one 64-token chunk: KNN-gather-mean in x-space (gather commutes with
// the linear projection), project via sWt, emit per-chunk BN partials.
// acc[4][4]: thread (tq,oq) holds tokens tq*4..+3 x outputs oq*4..+3.
__device__ __forceinline__ void process_chunk(
    int ch, const f4* __restrict__ x4, const int* __restrict__ knn,
    const float (*sWt)[CC], float (*uagg)[CC + 4], float (*ured)[16][CC],
    float* __restrict__ partials, float acc[4][4])
{
    const int tid = threadIdx.x;
    const int g = tid >> 4, l = tid & 15;
    const int batch = ch & 7;
    const int nb = (ch >> 3) * TPB;

    __syncthreads();   // guard u reuse across calls; orders sWt load on 1st call

    #pragma unroll
    for (int it = 0; it < 4; ++it) {
        const int t = it * 16 + g;
        const int idx_my =
            __builtin_nontemporal_load(&knn[(batch * NN + nb + t) * KK + l]);
        float sx = 0.f, sy = 0.f, sz = 0.f, sw = 0.f;
        #pragma unroll
        for (int k = 0; k < KK; ++k) {
            const int idx = __shfl(idx_my, k, 16);
            const f4 v = x4[(size_t)(batch * NN + idx) * (CC / 4) + l];
            sx += v.x; sy += v.y; sz += v.z; sw += v.w;
        }
        const float inv = 1.0f / KK;
        f4 r; r.x = sx * inv; r.y = sy * inv; r.z = sz * inv; r.w = sw * inv;
        *(f4*)&uagg[t][l * 4] = r;
    }
    __syncthreads();

    const int tq = tid >> 4, oq = tid & 15;
    #pragma unroll
    for (int t = 0; t < 4; ++t)
        #pragma unroll
        for (int o = 0; o < 4; ++o) acc[t][o] = 0.f;

    #pragma unroll
    for (int c4 = 0; c4 < CC; c4 += 4) {
        float av[4][4], wv[4][4];
        #pragma unroll
        for (int t = 0; t < 4; ++t) {
            const f4 tmp = *(const f4*)&uagg[tq * 4 + t][c4];
            av[t][0] = tmp.x; av[t][1] = tmp.y; av[t][2] = tmp.z; av[t][3] = tmp.w;
        }
        #pragma unroll
        for (int cc = 0; cc < 4; ++cc) {
            const f4 tmp = *(const f4*)&sWt[c4 + cc][oq * 4];
            wv[cc][0] = tmp.x; wv[cc][1] = tmp.y; wv[cc][2] = tmp.z; wv[cc][3] = tmp.w;
        }
        #pragma unroll
        for (int t = 0; t < 4; ++t)
            #pragma unroll
            for (int cc = 0; cc < 4; ++cc)
                #pragma unroll
                for (int o = 0; o < 4; ++o)
                    acc[t][o] += av[t][cc] * wv[cc][o];
    }
    __syncthreads();   // before overwriting uagg with ured

    float ps[4] = {}, pq[4] = {};
    #pragma unroll
    for (int t = 0; t < 4; ++t)
        #pragma unroll
        for (int o = 0; o < 4; ++o) {
            ps[o] += acc[t][o];
            pq[o] += acc[t][o] * acc[t][o];
        }
    #pragma unroll
    for (int o = 0; o < 4; ++o) {
        ured[0][tq][oq * 4 + o] = ps[o];
        ured[1][tq][oq * 4 + o] = pq[o];
    }
    __syncthreads();
    if (tid < 128) {                       // 0..63 sum, 64..127 sumsq
        const int w = tid >> 6, c = tid & 63;
        float s = 0.f;
        #pragma unroll
        for (int i = 0; i < 16; ++i) s += ured[w][i][c];
        __builtin_nontemporal_store(s, &partials[(size_t)tid * NCHUNK + ch]);
    }
}

// ---------------- Cooperative single-dispatch path ----------------
__global__ __launch_bounds__(THREADS, 4) void k_coop(
    const float* __restrict__ x, const int* __restrict__ knn,
    const float* __restrict__ W, const float* __restrict__ gamma,
    const float* __restrict__ beta, float* __restrict__ out,
    float* __restrict__ partials, float* __restrict__ ss)
{
    __shared__ float sWt[CC][CC];
    __shared__ union { float agg[TPB][CC + 4]; float red[2][16][CC]; } u;
    __shared__ float sFin[8];

    const int tid = threadIdx.x;
    const int R = gridDim.x;
    for (int i = tid; i < CC * CC; i += THREADS) sWt[i & 63][i >> 6] = W[i];

    const int tq = tid >> 4, oq = tid & 15;
    f4* out4 = (f4*)out;
    float acc[4][4];

    // Extra chunks (only if R < NCHUNK): dump raw agg to out, normalize later.
    for (int ch = blockIdx.x + R; ch < NCHUNK; ch += R) {
        process_chunk(ch, (const f4*)x, knn, sWt, u.agg, u.red, partials, acc);
        const int batch = ch & 7, nb = (ch >> 3) * TPB;
        #pragma unroll
        for (int t = 0; t < 4; ++t) {
            f4 r; r.x = acc[t][0]; r.y = acc[t][1]; r.z = acc[t][2]; r.w = acc[t][3];
            out4[(size_t)(batch * NN + nb + tq * 4 + t) * (CC / 4) + oq] = r;
        }
    }
    // Owned chunk stays in registers across the grid sync.
    process_chunk(blockIdx.x, (const f4*)x, knn, sWt, u.agg, u.red, partials, acc);

    __threadfence();
    cg::this_grid().sync();

    if (blockIdx.x < 64) {                  // channel j = blockIdx.x
        const int j = blockIdx.x;
        float s1 = 0.f, s2 = 0.f;
        for (int i = tid; i < NCHUNK; i += THREADS) {
            s1 += partials[j * NCHUNK + i];
            s2 += partials[(64 + j) * NCHUNK + i];
        }
        #pragma unroll
        for (int off = 32; off; off >>= 1) {
            s1 += __shfl_down(s1, off);
            s2 += __shfl_down(s2, off);
        }
        if ((tid & 63) == 0) { sFin[tid >> 6] = s1; sFin[4 + (tid >> 6)] = s2; }
        __syncthreads();
        if (tid == 0) {
            const float S1 = sFin[0] + sFin[1] + sFin[2] + sFin[3];
            const float S2 = sFin[4] + sFin[5] + sFin[6] + sFin[7];
            const float invn = 1.0f / (float)NTOK;
            const float mu  = S1 * invn;
            const float var = S2 * invn - mu * mu;
            const float sc  = gamma[j] * rsqrtf(var + BN_EPS);
            ss[j]      = sc;
            ss[CC + j] = beta[j] - mu * sc;
        }
    }
    __threadfence();
    cg::this_grid().sync();

    const f4 sc4 = ((const f4*)ss)[oq];
    const f4 sh4 = ((const f4*)ss)[CC / 4 + oq];
    {   // owned chunk: normalize from registers, single final write
        const int batch = blockIdx.x & 7, nb = (blockIdx.x >> 3) * TPB;
        #pragma unroll
        for (int t = 0; t < 4; ++t) {
            f4 r;
            r.x = fmaf(acc[t][0], sc4.x, sh4.x);
            r.y = fmaf(acc[t][1], sc4.y, sh4.y);
            r.z = fmaf(acc[t][2], sc4.z, sh4.z);
            r.w = fmaf(acc[t][3], sc4.w, sh4.w);
            __builtin_nontemporal_store(
                r, &out4[(size_t)(batch * NN + nb + tq * 4 + t) * (CC / 4) + oq]);
        }
    }
    for (int ch = blockIdx.x + R; ch < NCHUNK; ch += R) {   // extras: in-place
        const int batch = ch & 7, nb = (ch >> 3) * TPB;
        #pragma unroll
        for (int t = 0; t < 4; ++t) {
            const size_t ix = (size_t)(batch * NN + nb + tq * 4 + t) * (CC / 4) + oq;
            const f4 a = out4[ix];
            f4 r;
            r.x = fmaf(a.x, sc4.x, sh4.x);
            r.y = fmaf(a.y, sc4.y, sh4.y);
            r.z = fmaf(a.z, sc4.z, sh4.z);
            r.w = fmaf(a.w, sc4.w, sh4.w);
            __builtin_nontemporal_store(r, &out4[ix]);
        }
    }
}

// ---------------- Fallback 3-kernel path (proven round-1 structure) ----------------
__global__ __launch_bounds__(THREADS, 4) void k_fb_main(
    const float* __restrict__ x, const int* __restrict__ knn,
    const float* __restrict__ W, float* __restrict__ out,
    float* __restrict__ partials)
{
    __shared__ float sWt[CC][CC];
    __shared__ union { float agg[TPB][CC + 4]; float red[2][16][CC]; } u;
    const int tid = threadIdx.x;
    for (int i = tid; i < CC * CC; i += THREADS) sWt[i & 63][i >> 6] = W[i];
    float acc[4][4];
    process_chunk(blockIdx.x, (const f4*)x, knn, sWt, u.agg, u.red, partials, acc);
    const int tq = tid >> 4, oq = tid & 15;
    const int batch = blockIdx.x & 7, nb = (blockIdx.x >> 3) * TPB;
    f4* out4 = (f4*)out;
    #pragma unroll
    for (int t = 0; t < 4; ++t) {
        f4 r; r.x = acc[t][0]; r.y = acc[t][1]; r.z = acc[t][2]; r.w = acc[t][3];
        out4[(size_t)(batch * NN + nb + tq * 4 + t) * (CC / 4) + oq] = r;
    }
}

__global__ __launch_bounds__(THREADS) void k_fb_stats(
    const float* __restrict__ partials, const float* __restrict__ gamma,
    const float* __restrict__ beta, float* __restrict__ ss)
{
    __shared__ float sFin[8];
    const int tid = threadIdx.x;
    const int j = blockIdx.x;
    float s1 = 0.f, s2 = 0.f;
    for (int i = tid; i < NCHUNK; i += THREADS) {
        s1 += partials[j * NCHUNK + i];
        s2 += partials[(64 + j) * NCHUNK + i];
    }
    #pragma unroll
    for (int off = 32; off; off >>= 1) {
        s1 += __shfl_down(s1, off);
        s2 += __shfl_down(s2, off);
    }
    if ((tid & 63) == 0) { sFin[tid >> 6] = s1; sFin[4 + (tid >> 6)] = s2; }
    __syncthreads();
    if (tid == 0) {
        const float S1 = sFin[0] + sFin[1] + sFin[2] + sFin[3];
        const float S2 = sFin[4] + sFin[5] + sFin[6] + sFin[7];
        const float invn = 1.0f / (float)NTOK;
        const float mu  = S1 * invn;
        const float var = S2 * invn - mu * mu;
        const float sc  = gamma[j] * rsqrtf(var + BN_EPS);
        ss[j]      = sc;
        ss[CC + j] = beta[j] - mu * sc;
    }
}

__global__ __launch_bounds__(256) void k_fb_norm(
    float* __restrict__ out, const float* __restrict__ ss)
{
    const int idx = blockIdx.x * 256 + threadIdx.x;   // f4 index
    f4* out4 = (f4*)out;
    const f4 a  = out4[idx];
    const int c4 = idx & (CC / 4 - 1);
    const f4 sc = ((const f4*)ss)[c4];
    const f4 sh = ((const f4*)ss)[CC / 4 + c4];
    f4 r;
    r.x = fmaf(a.x, sc.x, sh.x);
    r.y = fmaf(a.y, sc.y, sh.y);
    r.z = fmaf(a.z, sc.z, sh.z);
    r.w = fmaf(a.w, sc.w, sh.w);
    __builtin_nontemporal_store(r, &out4[idx]);
}

extern "C" void kernel_launch(void* const* d_in, const int* in_sizes, int n_in,
                              void* d_out, int out_size, void* d_ws, size_t ws_size,
                              hipStream_t stream)
{
    const float* x     = (const float*)d_in[0];
    const int*   knn   = (const int*)d_in[1];
    const float* W     = (const float*)d_in[2];
    const float* gamma = (const float*)d_in[3];
    const float* beta  = (const float*)d_in[4];
    float* out = (float*)d_out;

    float* partials = (float*)d_ws;              // 128*1024 floats
    float* ss       = partials + 128 * NCHUNK;   // 128 floats

    // Host-side queries are capture-safe (not stream-ordered) and not timed.
    int R = 0;
    {
        int dev = 0;
        (void)hipGetDevice(&dev);
        hipDeviceProp_t prop;
        if (hipGetDeviceProperties(&prop, dev) == hipSuccess && prop.cooperativeLaunch) {
            int maxB = 0;
            if (hipOccupancyMaxActiveBlocksPerMultiprocessor(&maxB, k_coop, THREADS, 0)
                    == hipSuccess && maxB > 0) {
                int r = maxB * prop.multiProcessorCount;
                if (r > NCHUNK) r = NCHUNK;
                r &= ~7;
                if (r >= 768) R = r;   // need >=3 blocks/CU to keep gather latency-hidden
            }
        }
    }

    if (R > 0) {
        void* args[] = {
            (void*)&x, (void*)&knn, (void*)&W, (void*)&gamma, (void*)&beta,
            (void*)&out, (void*)&partials, (void*)&ss
        };
        if (hipLaunchCooperativeKernel((void*)k_coop, dim3(R), dim3(THREADS),
                                       args, 0, stream) == hipSuccess)
            return;
    }

    // Fallback: proven 3-kernel pipeline
    k_fb_main<<<NCHUNK, THREADS, 0, stream>>>(x, knn, W, out, partials);
    k_fb_stats<<<64, THREADS, 0, stream>>>(partials, gamma, beta, ss);
    k_fb_norm<<<(NTOK * CC) / 4 / 256, 256, 0, stream>>>(out, ss);
}

// Round 4
// 41.615 us; speedup vs baseline: 1.0400x; 1.0400x over previous
//
#include <hip/hip_runtime.h>

typedef float f4 __attribute__((ext_vector_type(4)));

// Problem constants: B=8, N=8192, K=16, C_in=C_out=64
#define BB 8
#define NN 8192
#define KK 16
#define CC 64
#define TPB 64                   // tokens per chunk/block in K1
#define THREADS 256
#define NCHUNK 1024              // 8 batches * 128 chunks
#define NTOK (BB * NN)
#define BN_EPS 1e-5f

// K1: KNN-gather-mean in x-space (gather commutes with the linear projection),
// project via LDS-held W^T, write agg into d_out, emit per-chunk BN partials.
// Gather issues all 16 neighbor loads per token before consuming (MLP).
__global__ __launch_bounds__(THREADS, 4) void k_main(
    const float* __restrict__ x, const int* __restrict__ knn,
    const float* __restrict__ W, float* __restrict__ out,
    float* __restrict__ partials)
{
    __shared__ float sWt[CC][CC];                         // W^T: sWt[c][o], 16KB
    __shared__ union { float agg[TPB][CC + 4]; float red[2][16][CC]; } u;

    const int tid   = threadIdx.x;
    const int batch = blockIdx.x & 7;     // round-robin XCD: pins batch's 2MB x slice
    const int nb    = (blockIdx.x >> 3) * TPB;

    for (int i = tid; i < CC * CC; i += THREADS)
        sWt[i & 63][i >> 6] = W[i];

    // ---- Phase A: gather-mean. 16 lanes per token; lane l owns channels 4l..4l+3.
    const int g = tid >> 4, l = tid & 15;
    const f4* __restrict__ x4b = (const f4*)x + (size_t)batch * NN * (CC / 4);

    for (int it = 0; it < 4; ++it) {
        const int t = it * 16 + g;
        const int idx_my =
            __builtin_nontemporal_load(&knn[(batch * NN + nb + t) * KK + l]);
        int idxs[16];
        #pragma unroll
        for (int k = 0; k < KK; ++k) idxs[k] = __shfl(idx_my, k, 16);
        f4 v[16];
        #pragma unroll
        for (int k = 0; k < KK; ++k) v[k] = x4b[idxs[k] * (CC / 4) + l];
        // tree reduction (better ILP + rounding)
        #pragma unroll
        for (int s = 8; s; s >>= 1)
            #pragma unroll
            for (int k = 0; k < s; ++k) v[k] += v[k + s];
        *(f4*)&u.agg[t][l * 4] = v[0] * (1.0f / KK);
    }
    __syncthreads();

    // ---- Phase B: projection. Thread (tq,oq) owns tokens tq*4..+3, outputs oq*4..+3.
    const int tq = tid >> 4, oq = tid & 15;
    float acc[4][4] = {};
    #pragma unroll
    for (int c4 = 0; c4 < CC; c4 += 4) {
        float av[4][4], wv[4][4];
        #pragma unroll
        for (int t = 0; t < 4; ++t) {
            const f4 tmp = *(const f4*)&u.agg[tq * 4 + t][c4];
            av[t][0] = tmp.x; av[t][1] = tmp.y; av[t][2] = tmp.z; av[t][3] = tmp.w;
        }
        #pragma unroll
        for (int cc = 0; cc < 4; ++cc) {
            const f4 tmp = *(const f4*)&sWt[c4 + cc][oq * 4];
            wv[cc][0] = tmp.x; wv[cc][1] = tmp.y; wv[cc][2] = tmp.z; wv[cc][3] = tmp.w;
        }
        #pragma unroll
        for (int t = 0; t < 4; ++t)
            #pragma unroll
            for (int cc = 0; cc < 4; ++cc)
                #pragma unroll
                for (int o = 0; o < 4; ++o)
                    acc[t][o] += av[t][cc] * wv[cc][o];
    }

    // ---- Write agg (into d_out)
    f4* __restrict__ out4 = (f4*)out;
    #pragma unroll
    for (int t = 0; t < 4; ++t) {
        f4 r; r.x = acc[t][0]; r.y = acc[t][1]; r.z = acc[t][2]; r.w = acc[t][3];
        out4[(size_t)(batch * NN + nb + tq * 4 + t) * (CC / 4) + oq] = r;
    }

    // ---- Per-chunk BN partials (coalesced layout: partials[chunk][128])
    __syncthreads();   // before overwriting u.agg with u.red
    float ps[4] = {}, pq[4] = {};
    #pragma unroll
    for (int t = 0; t < 4; ++t)
        #pragma unroll
        for (int o = 0; o < 4; ++o) {
            ps[o] += acc[t][o];
            pq[o] += acc[t][o] * acc[t][o];
        }
    #pragma unroll
    for (int o = 0; o < 4; ++o) {
        u.red[0][tq][oq * 4 + o] = ps[o];
        u.red[1][tq][oq * 4 + o] = pq[o];
    }
    __syncthreads();
    if (tid < 128) {                       // 0..63 = sum(c), 64..127 = sumsq(c)
        const int w = tid >> 6, c = tid & 63;
        float s = 0.f;
        #pragma unroll
        for (int i = 0; i < 16; ++i) s += u.red[w][i][c];
        partials[(size_t)blockIdx.x * 128 + tid] = s;   // 512B contiguous per block
    }
}

// K2: finalize BN stats -> ss[0..63]=scale, ss[64..127]=shift
__global__ __launch_bounds__(THREADS) void k_stats(
    const float* __restrict__ partials, const float* __restrict__ gamma,
    const float* __restrict__ beta, float* __restrict__ ss)
{
    __shared__ float sFin[8];
    const int tid = threadIdx.x;
    const int j = blockIdx.x;            // channel 0..63
    float s1 = 0.f, s2 = 0.f;
    for (int i = tid; i < NCHUNK; i += THREADS) {
        s1 += partials[(size_t)i * 128 + j];
        s2 += partials[(size_t)i * 128 + 64 + j];
    }
    #pragma unroll
    for (int off = 32; off; off >>= 1) {
        s1 += __shfl_down(s1, off);
        s2 += __shfl_down(s2, off);
    }
    if ((tid & 63) == 0) { sFin[tid >> 6] = s1; sFin[4 + (tid >> 6)] = s2; }
    __syncthreads();
    if (tid == 0) {
        const float S1 = sFin[0] + sFin[1] + sFin[2] + sFin[3];
        const float S2 = sFin[4] + sFin[5] + sFin[6] + sFin[7];
        const float invn = 1.0f / (float)NTOK;
        const float mu  = S1 * invn;
        const float var = S2 * invn - mu * mu;
        const float sc  = gamma[j] * rsqrtf(var + BN_EPS);
        ss[j]      = sc;
        ss[CC + j] = beta[j] - mu * sc;
    }
}

// K3: in-place normalize d_out: out = agg*scale[c] + shift[c]  (pure 32MB stream)
__global__ __launch_bounds__(256) void k_norm(
    float* __restrict__ out, const float* __restrict__ ss)
{
    const int idx = blockIdx.x * 256 + threadIdx.x;   // f4 index
    f4* out4 = (f4*)out;
    const f4 a  = out4[idx];
    const int c4 = idx & (CC / 4 - 1);
    const f4 sc = ((const f4*)ss)[c4];
    const f4 sh = ((const f4*)ss)[CC / 4 + c4];
    f4 r;
    r.x = fmaf(a.x, sc.x, sh.x);
    r.y = fmaf(a.y, sc.y, sh.y);
    r.z = fmaf(a.z, sc.z, sh.z);
    r.w = fmaf(a.w, sc.w, sh.w);
    __builtin_nontemporal_store(r, &out4[idx]);
}

extern "C" void kernel_launch(void* const* d_in, const int* in_sizes, int n_in,
                              void* d_out, int out_size, void* d_ws, size_t ws_size,
                              hipStream_t stream)
{
    const float* x     = (const float*)d_in[0];
    const int*   knn   = (const int*)d_in[1];
    const float* W     = (const float*)d_in[2];
    const float* gamma = (const float*)d_in[3];
    const float* beta  = (const float*)d_in[4];
    float* out = (float*)d_out;

    float* partials = (float*)d_ws;              // 1024*128 floats
    float* ss       = partials + NCHUNK * 128;   // 128 floats

    k_main <<<NCHUNK, THREADS, 0, stream>>>(x, knn, W, out, partials);
    k_stats<<<64, THREADS, 0, stream>>>(partials, gamma, beta, ss);
    k_norm <<<(NTOK * CC) / 4 / 256, 256, 0, stream>>>(out, ss);
}

// Round 5
// 40.741 us; speedup vs baseline: 1.0623x; 1.0215x over previous
//
#include <hip/hip_runtime.h>

typedef float f4 __attribute__((ext_vector_type(4)));

// Problem constants: B=8, N=8192, K=16, C_in=C_out=64
#define BB 8
#define NN 8192
#define KK 16
#define CC 64
#define TPB 64                   // tokens per chunk/block in K1
#define THREADS 256
#define NCHUNK 1024              // 8 batches * 128 chunks
#define NTOK (BB * NN)
#define BN_EPS 1e-5f

// K1: KNN-gather-mean in x-space (gather commutes with the linear projection),
// project via LDS-held W^T, write agg into d_out (NON-TEMPORAL: protect the
// per-XCD L2 copy of this batch's x slice from write-allocate eviction),
// emit per-chunk BN partials.
__global__ __launch_bounds__(THREADS, 4) void k_main(
    const float* __restrict__ x, const int* __restrict__ knn,
    const float* __restrict__ W, float* __restrict__ out,
    float* __restrict__ partials)
{
    __shared__ float sWt[CC][CC];                         // W^T: sWt[c][o], 16KB
    __shared__ union { float agg[TPB][CC + 4]; float red[2][16][CC]; } u;

    const int tid   = threadIdx.x;
    const int batch = blockIdx.x & 7;     // round-robin XCD: pins batch's 2MB x slice
    const int nb    = (blockIdx.x >> 3) * TPB;

    for (int i = tid; i < CC * CC; i += THREADS)
        sWt[i & 63][i >> 6] = W[i];

    // ---- Phase A: gather-mean. 16 lanes per token; lane l owns channels 4l..4l+3.
    const int g = tid >> 4, l = tid & 15;
    const f4* __restrict__ x4b = (const f4*)x + (size_t)batch * NN * (CC / 4);

    for (int it = 0; it < 4; ++it) {
        const int t = it * 16 + g;
        const int idx_my =
            __builtin_nontemporal_load(&knn[(batch * NN + nb + t) * KK + l]);
        int idxs[16];
        #pragma unroll
        for (int k = 0; k < KK; ++k) idxs[k] = __shfl(idx_my, k, 16);
        f4 v[16];
        #pragma unroll
        for (int k = 0; k < KK; ++k) v[k] = x4b[idxs[k] * (CC / 4) + l];
        #pragma unroll
        for (int s = 8; s; s >>= 1)
            #pragma unroll
            for (int k = 0; k < s; ++k) v[k] += v[k + s];
        *(f4*)&u.agg[t][l * 4] = v[0] * (1.0f / KK);
    }
    __syncthreads();

    // ---- Phase B: projection. Thread (tq,oq) owns tokens tq*4..+3, outputs oq*4..+3.
    const int tq = tid >> 4, oq = tid & 15;
    float acc[4][4] = {};
    #pragma unroll
    for (int c4 = 0; c4 < CC; c4 += 4) {
        float av[4][4], wv[4][4];
        #pragma unroll
        for (int t = 0; t < 4; ++t) {
            const f4 tmp = *(const f4*)&u.agg[tq * 4 + t][c4];
            av[t][0] = tmp.x; av[t][1] = tmp.y; av[t][2] = tmp.z; av[t][3] = tmp.w;
        }
        #pragma unroll
        for (int cc = 0; cc < 4; ++cc) {
            const f4 tmp = *(const f4*)&sWt[c4 + cc][oq * 4];
            wv[cc][0] = tmp.x; wv[cc][1] = tmp.y; wv[cc][2] = tmp.z; wv[cc][3] = tmp.w;
        }
        #pragma unroll
        for (int t = 0; t < 4; ++t)
            #pragma unroll
            for (int cc = 0; cc < 4; ++cc)
                #pragma unroll
                for (int o = 0; o < 4; ++o)
                    acc[t][o] += av[t][cc] * wv[cc][o];
    }

    // ---- Write agg (into d_out) — non-temporal: bypass L2 allocate
    f4* __restrict__ out4 = (f4*)out;
    #pragma unroll
    for (int t = 0; t < 4; ++t) {
        f4 r; r.x = acc[t][0]; r.y = acc[t][1]; r.z = acc[t][2]; r.w = acc[t][3];
        __builtin_nontemporal_store(
            r, &out4[(size_t)(batch * NN + nb + tq * 4 + t) * (CC / 4) + oq]);
    }

    // ---- Per-chunk BN partials (coalesced layout: partials[chunk][128])
    __syncthreads();   // before overwriting u.agg with u.red
    float ps[4] = {}, pq[4] = {};
    #pragma unroll
    for (int t = 0; t < 4; ++t)
        #pragma unroll
        for (int o = 0; o < 4; ++o) {
            ps[o] += acc[t][o];
            pq[o] += acc[t][o] * acc[t][o];
        }
    #pragma unroll
    for (int o = 0; o < 4; ++o) {
        u.red[0][tq][oq * 4 + o] = ps[o];
        u.red[1][tq][oq * 4 + o] = pq[o];
    }
    __syncthreads();
    if (tid < 128) {                       // 0..63 = sum(c), 64..127 = sumsq(c)
        const int w = tid >> 6, c = tid & 63;
        float s = 0.f;
        #pragma unroll
        for (int i = 0; i < 16; ++i) s += u.red[w][i][c];
        partials[(size_t)blockIdx.x * 128 + tid] = s;   // normal store: L2-resident for k_stats
    }
}

// K2: finalize BN stats -> ss[0..63]=scale, ss[64..127]=shift
__global__ __launch_bounds__(THREADS) void k_stats(
    const float* __restrict__ partials, const float* __restrict__ gamma,
    const float* __restrict__ beta, float* __restrict__ ss)
{
    __shared__ float sFin[8];
    const int tid = threadIdx.x;
    const int j = blockIdx.x;            // channel 0..63
    float s1 = 0.f, s2 = 0.f;
    for (int i = tid; i < NCHUNK; i += THREADS) {
        s1 += partials[(size_t)i * 128 + j];
        s2 += partials[(size_t)i * 128 + 64 + j];
    }
    #pragma unroll
    for (int off = 32; off; off >>= 1) {
        s1 += __shfl_down(s1, off);
        s2 += __shfl_down(s2, off);
    }
    if ((tid & 63) == 0) { sFin[tid >> 6] = s1; sFin[4 + (tid >> 6)] = s2; }
    __syncthreads();
    if (tid == 0) {
        const float S1 = sFin[0] + sFin[1] + sFin[2] + sFin[3];
        const float S2 = sFin[4] + sFin[5] + sFin[6] + sFin[7];
        const float invn = 1.0f / (float)NTOK;
        const float mu  = S1 * invn;
        const float var = S2 * invn - mu * mu;
        const float sc  = gamma[j] * rsqrtf(var + BN_EPS);
        ss[j]      = sc;
        ss[CC + j] = beta[j] - mu * sc;
    }
}

// K3: in-place normalize d_out: out = agg*scale[c] + shift[c]  (32MB stream, L3-fed)
__global__ __launch_bounds__(256) void k_norm(
    float* __restrict__ out, const float* __restrict__ ss)
{
    const int idx = blockIdx.x * 256 + threadIdx.x;   // f4 index
    f4* out4 = (f4*)out;
    const f4 a  = out4[idx];
    const int c4 = idx & (CC / 4 - 1);
    const f4 sc = ((const f4*)ss)[c4];
    const f4 sh = ((const f4*)ss)[CC / 4 + c4];
    f4 r;
    r.x = fmaf(a.x, sc.x, sh.x);
    r.y = fmaf(a.y, sc.y, sh.y);
    r.z = fmaf(a.z, sc.z, sh.z);
    r.w = fmaf(a.w, sc.w, sh.w);
    __builtin_nontemporal_store(r, &out4[idx]);
}

extern "C" void kernel_launch(void* const* d_in, const int* in_sizes, int n_in,
                              void* d_out, int out_size, void* d_ws, size_t ws_size,
                              hipStream_t stream)
{
    const float* x     = (const float*)d_in[0];
    const int*   knn   = (const int*)d_in[1];
    const float* W     = (const float*)d_in[2];
    const float* gamma = (const float*)d_in[3];
    const float* beta  = (const float*)d_in[4];
    float* out = (float*)d_out;

    float* partials = (float*)d_ws;              // 1024*128 floats
    float* ss       = partials + NCHUNK * 128;   // 128 floats

    k_main <<<NCHUNK, THREADS, 0, stream>>>(x, knn, W, out, partials);
    k_stats<<<64, THREADS, 0, stream>>>(partials, gamma, beta, ss);
    k_norm <<<(NTOK * CC) / 4 / 256, 256, 0, stream>>>(out, ss);
}